// Round 3
// baseline (51.910 us; speedup 1.0000x reference)
//
#include <hip/hip_runtime.h>

// DimeNet Bessel radial basis with smooth cutoff envelope.
// out[e][k] = env(d/c) * sin(freq[k] * d/c),  d = |R[idx_i[e]] - R[idx_j[e]]|
// env(x) = 1/x + a*x^5 + b*x^6 + c*x^7, p=6: a=-28, b=48, c=-21
//
// 4 threads per edge (coalesced 16B-stride stores, from round 2), plus:
// each R row (12 B) is gathered with ONE dwordx4 (16 B, 4B-aligned) instead
// of 3 scalar dword loads -> gather line-touches per edge drop 6 -> 2,
// pulling L1/TA occupancy below the HBM write-stream floor.
// The 4 B overread is guarded for the final node row only.

#define NUM_RADIAL 16
constexpr float INV_CUTOFF = 1.0f / 5.0f;

// 16B vector with 4B alignment: CDNA global_load_dwordx4 only needs dword
// alignment, and R rows start at 12*i bytes.
typedef float f4u __attribute__((ext_vector_type(4), aligned(4)));

__global__ __launch_bounds__(256) void dimenet_rbf_kernel(
    const float* __restrict__ R,
    const float* __restrict__ freq,
    const int* __restrict__ idx_i,
    const int* __restrict__ idx_j,
    float* __restrict__ out,
    int nE, int nR3)  // nR3 = 3 * N_NODES
{
    int tid = blockIdx.x * blockDim.x + threadIdx.x;
    int e = tid >> 2;       // edge index (4 consecutive lanes share an edge)
    int q = tid & 3;        // which float4 quarter of the 16-wide rbf row
    if (e >= nE) return;

    int i = idx_i[e];
    int j = idx_j[e];

    float xi, yi, zi, xj, yj, zj;
    if (3 * i + 4 <= nR3) {   // safe to overread 4 B
        f4u ri = *reinterpret_cast<const f4u*>(R + 3 * i);
        xi = ri.x; yi = ri.y; zi = ri.z;
    } else {                  // last node row: scalar fallback (rare)
        xi = R[3 * i]; yi = R[3 * i + 1]; zi = R[3 * i + 2];
    }
    if (3 * j + 4 <= nR3) {
        f4u rj = *reinterpret_cast<const f4u*>(R + 3 * j);
        xj = rj.x; yj = rj.y; zj = rj.z;
    } else {
        xj = R[3 * j]; yj = R[3 * j + 1]; zj = R[3 * j + 2];
    }

    float dx = xi - xj;
    float dy = yi - yj;
    float dz = zi - zj;
    float d2 = dx * dx + dy * dy + dz * dz;
    float d  = sqrtf(fmaxf(d2, 0.0f));

    float x = d * INV_CUTOFF;

    // envelope: 1/x + x^5 * (a + b*x + c*x^2), a=-28, b=48, c=-21
    float x2 = x * x;
    float x5 = x2 * x2 * x;
    float poly = -28.0f + x * (48.0f + x * (-21.0f));
    float env = __builtin_amdgcn_rcpf(x) + x5 * poly;

    // this thread's 4 radial frequencies, one 16B load (freq base is aligned)
    float4 f = reinterpret_cast<const float4*>(freq)[q];

    float4 v;
    v.x = env * __sinf(f.x * x);
    v.y = env * __sinf(f.y * x);
    v.z = env * __sinf(f.z * x);
    v.w = env * __sinf(f.w * x);

    // contiguous across lanes: thread tid writes out[tid*4 .. tid*4+3]
    reinterpret_cast<float4*>(out)[tid] = v;
}

extern "C" void kernel_launch(void* const* d_in, const int* in_sizes, int n_in,
                              void* d_out, int out_size, void* d_ws, size_t ws_size,
                              hipStream_t stream)
{
    const float* R     = (const float*)d_in[0];
    const float* freq  = (const float*)d_in[1];
    const int*   idx_i = (const int*)d_in[2];
    const int*   idx_j = (const int*)d_in[3];
    float* out = (float*)d_out;

    int nE  = in_sizes[2];
    int nR3 = in_sizes[0];   // flat element count of R = 3 * N_NODES

    int block = 256;
    long long nthreads = 4LL * nE;
    int grid = (int)((nthreads + block - 1) / block);
    dimenet_rbf_kernel<<<grid, block, 0, stream>>>(R, freq, idx_i, idx_j, out, nE, nR3);
}